// Round 8
// baseline (856.745 us; speedup 1.0000x reference)
//
#include <hip/hip_runtime.h>
#include <hip/hip_fp16.h>

#define B_ 512
#define T_ 512
#define H_ 64
#define K_ 4

// ws layout:
//   wht  f16 [K*3][8][64][8]  @ 0        (98304 B)  chunk-transposed W_h
//   wit  f16 [3][8][64][8]    @ 98304    (24576 B)  chunk-transposed W_i
//   flag int                  @ 123136
//   ip planes (variant A): ipr/ipz/ipn f16 [B*T][64] @ 131072, plane stride 33554432
#define WS_WIT_OFF   98304
#define WS_FLAG_OFF  123136
#define WS_IP_OFF    131072
#define IP_PLANE     33554432ull
#define WS_A_NEED    (131072ull + 3ull * 33554432ull)   // ~96.2 MB

typedef _Float16 half2_t __attribute__((ext_vector_type(2)));

union Q { uint4 u; half2_t h[4]; };  // 16 B = 4 packed half2

__device__ __forceinline__ float fdot2f(half2_t a, half2_t b, float c) {
#if __has_builtin(__builtin_amdgcn_fdot2)
    return __builtin_amdgcn_fdot2(a, b, c, false);
#else
    return fmaf((float)a[0], (float)b[0], fmaf((float)a[1], (float)b[1], c));
#endif
}

__device__ __forceinline__ half2_t pkh2(float a, float b) {
    return __builtin_bit_cast(half2_t, __builtin_amdgcn_cvt_pkrtz(a, b));
}

// Detect whether mask buffer is 1-byte bools or int32 0/1 (little-endian).
__global__ void detect_mask_kernel(const unsigned char* __restrict__ mb, int* __restrict__ flag) {
    __shared__ int cnt;
    if (threadIdx.x == 0) cnt = 0;
    __syncthreads();
    int c = 0;
    for (int i = threadIdx.x; i < 4096; i += blockDim.x)
        if ((i & 3) != 0 && mb[i] != 0) c++;
    atomicAdd(&cnt, c);
    __syncthreads();
    if (threadIdx.x == 0) *flag = (cnt > 0) ? 1 : 0;  // 1 => uint8 bools, 0 => int32
}

// Weights -> f16 chunk-transposed: dst u4 index (mat*8 + j/8)*64 + i
__global__ void convert_weights_kernel(const float* __restrict__ Whr, const float* __restrict__ Whz,
                                       const float* __restrict__ Whn, const float* __restrict__ Wir,
                                       const float* __restrict__ Wiz, const float* __restrict__ Win,
                                       __half* __restrict__ wht, __half* __restrict__ wit) {
    int idx = blockIdx.x * 256 + threadIdx.x;
    if (idx < K_ * 3 * H_ * H_) {
        int mat = idx >> 12;            // k*3+g
        int i   = (idx >> 6) & 63;
        int j   = idx & 63;
        int k   = mat / 3, g = mat - 3 * k;
        const float* src = (g == 0) ? Whr : (g == 1) ? Whz : Whn;
        wht[((mat * 8 + (j >> 3)) * 64 + i) * 8 + (j & 7)] = __float2half(src[(k * H_ + i) * H_ + j]);
    }
    if (idx < 3 * H_ * H_) {
        int g = idx >> 12;
        int i = (idx >> 6) & 63;
        int j = idx & 63;
        const float* src = (g == 0) ? Wir : (g == 1) ? Wiz : Win;
        wit[((g * 8 + (j >> 3)) * 64 + i) * 8 + (j & 7)] = __float2half(src[i * H_ + j]);
    }
}

// Input-projection pre-pass: ip_g[bt][i] = dot(x[bt,:], W_ig[i,:]) + b_g[i], f16.
// 2048 waves, 128 bt each; W_i in registers; x row via wave-uniform float4 loads.
__global__ __launch_bounds__(256, 2)
void ip_prepass(const float* __restrict__ xf, const __half* __restrict__ wit_g,
                const float* __restrict__ b_ir, const float* __restrict__ b_iz,
                const float* __restrict__ b_in,
                __half* __restrict__ ipr, __half* __restrict__ ipz, __half* __restrict__ ipn) {
    const int lane = threadIdx.x & 63;
    const int wvid = blockIdx.x * 4 + (threadIdx.x >> 6);   // 0..2047
    Q wr[8], wz[8], wn[8];
    const uint4* wu = (const uint4*)wit_g;
#pragma unroll
    for (int q = 0; q < 8; q++) {
        wr[q].u = wu[(0 * 8 + q) * 64 + lane];
        wz[q].u = wu[(1 * 8 + q) * 64 + lane];
        wn[q].u = wu[(2 * 8 + q) * 64 + lane];
    }
    const float br = b_ir[lane], bz = b_iz[lane], bn = b_in[lane];
    const int bt0 = wvid * ((B_ * T_) / 2048);              // 128 bt per wave
#pragma unroll 1
    for (int n = 0; n < (B_ * T_) / 2048; n++) {
        const int bt = bt0 + n;
        const float4* xr = (const float4*)(xf + (size_t)bt * H_);
        Q xq[8];
#pragma unroll
        for (int q = 0; q < 8; q++) {
            float4 a = xr[2 * q], c = xr[2 * q + 1];
            xq[q].h[0] = pkh2(a.x, a.y); xq[q].h[1] = pkh2(a.z, a.w);
            xq[q].h[2] = pkh2(c.x, c.y); xq[q].h[3] = pkh2(c.z, c.w);
        }
        float sr = br, sz = bz, sn = bn;
#pragma unroll
        for (int q = 0; q < 8; q++)
#pragma unroll
            for (int p = 0; p < 4; p++) {
                sr = fdot2f(wr[q].h[p], xq[q].h[p], sr);
                sz = fdot2f(wz[q].h[p], xq[q].h[p], sz);
                sn = fdot2f(wn[q].h[p], xq[q].h[p], sn);
            }
        const size_t o = (size_t)bt * H_ + lane;
        ipr[o] = __float2half(sr); ipz[o] = __float2half(sz); ipn[o] = __float2half(sn);
    }
}

#define MATVEC(W)                                                          \
    {                                                                      \
        _Pragma("unroll") for (int q = 0; q < 8; q++) {                    \
            _Pragma("unroll") for (int p = 0; p < 4; p++) {                \
                shr = fdot2f(W##r[q].h[p], hq[q].h[p], shr);               \
                shz = fdot2f(W##z[q].h[p], hq[q].h[p], shz);               \
                shn = fdot2f(W##n[q].h[p], hq[q].h[p], shn);               \
            }                                                              \
        }                                                                  \
    }

#define LOADE(E)                                                           \
    _Pragma("unroll") for (int q = 0; q < 8; q++) {                        \
        w##E##r[q].u = whu[((E * 3 + 0) * 8 + q) * 64 + lane];             \
        w##E##z[q].u = whu[((E * 3 + 1) * 8 + q) * 64 + lane];             \
        w##E##n[q].u = whu[((E * 3 + 2) * 8 + q) * 64 + lane];             \
    }

// Sequential GRU: one wave per batch element, 512 blocks x 64 threads.
// ALL 4 experts' W_h live in VGPRs (384); kc is wave-uniform -> 4-way switch,
// statically-indexed matvec per expert. Zero weight memory traffic per step.
// MODE 0: ip precomputed (f16 planes, prefetch distance 2). MODE 1: in-loop
// ip from LDS W_i + wave-uniform f32 x loads (any ws size).
template <int MODE>
__global__ __launch_bounds__(64, 1)
void gru_seq3(const float* __restrict__ xf, const int* __restrict__ ctx,
              const unsigned char* __restrict__ maskb, const int* __restrict__ flagp,
              const __half* __restrict__ wht, const __half* __restrict__ wit,
              const __half* __restrict__ ipr, const __half* __restrict__ ipz,
              const __half* __restrict__ ipn,
              const float* __restrict__ b_ir, const float* __restrict__ b_iz,
              const float* __restrict__ b_in, const float* __restrict__ b_hr,
              const float* __restrict__ b_hz, const float* __restrict__ b_hn,
              const float* __restrict__ Wo_w, const float* __restrict__ Wo_b,
              float* __restrict__ out) {
    __shared__ __align__(16) __half hsc[2][64];
    __shared__ uint4 swi[MODE ? 1536 : 8];

    const int lane = threadIdx.x;   // 0..63, one wave per block
    const int b    = blockIdx.x;
    const int bt0  = b * T_;
    const int flag   = *flagp;
    const int mshift = flag ? 0 : 2;

    // ---- all 4 experts' W_h into VGPRs (384) ----
    Q w0r[8], w0z[8], w0n[8], w1r[8], w1z[8], w1n[8];
    Q w2r[8], w2z[8], w2n[8], w3r[8], w3z[8], w3n[8];
    const uint4* whu = (const uint4*)wht;
    LOADE(0) LOADE(1) LOADE(2) LOADE(3)

    // per-expert hidden biases (12 VGPRs)
    const float bhr0 = b_hr[lane],       bhz0 = b_hz[lane],       bhn0 = b_hn[lane];
    const float bhr1 = b_hr[64 + lane],  bhz1 = b_hz[64 + lane],  bhn1 = b_hn[64 + lane];
    const float bhr2 = b_hr[128 + lane], bhz2 = b_hz[128 + lane], bhn2 = b_hn[128 + lane];
    const float bhr3 = b_hr[192 + lane], bhz3 = b_hz[192 + lane], bhn3 = b_hn[192 + lane];

    const float wo0 = Wo_w[lane], wo1 = Wo_w[64 + lane];
    const float wob0 = Wo_b[0], wob1 = Wo_b[1];

    float bir = 0.f, biz = 0.f, bin = 0.f;
    if constexpr (MODE == 1) {
        // stage W_i into LDS (24 KB)
        const uint4* wiu = (const uint4*)wit;
#pragma unroll 1
        for (int i = lane; i < 1536; i += 64) swi[i] = wiu[i];
        __syncthreads();
        bir = b_ir[lane]; biz = b_iz[lane]; bin = b_in[lane];
    }

    float hreg = 0.0f;
    Q hq[8];
#pragma unroll
    for (int q = 0; q < 8; q++) hq[q].u = make_uint4(0u, 0u, 0u, 0u);

    // ---- prologue ----
    __half cr{}, cz{}, cn{}, nr{}, nz{}, nn{};
    Q xq[8];
    if constexpr (MODE == 0) {
        const size_t o0 = (size_t)bt0 * H_ + lane;
        cr = ipr[o0]; cz = ipz[o0]; cn = ipn[o0];
        const size_t o1 = (size_t)(bt0 + 1) * H_ + lane;
        nr = ipr[o1]; nz = ipz[o1]; nn = ipn[o1];
    } else {
        const float4* xr = (const float4*)(xf + (size_t)bt0 * H_);
#pragma unroll
        for (int q = 0; q < 8; q++) {
            float4 a = xr[2 * q], c = xr[2 * q + 1];
            xq[q].h[0] = pkh2(a.x, a.y); xq[q].h[1] = pkh2(a.z, a.w);
            xq[q].h[2] = pkh2(c.x, c.y); xq[q].h[3] = pkh2(c.z, c.w);
        }
    }
    int   kc = __builtin_amdgcn_readfirstlane(ctx[bt0]);
    float mc = maskb[(size_t)bt0 << mshift] ? 1.0f : 0.0f;

    float* outp = out + (size_t)b * T_ * 2;

#pragma unroll 1
    for (int t = 0; t < T_; t++) {
        const int tn  = (t + 1 < T_) ? (t + 1) : t;
        const int btn = bt0 + tn;

        // ---- prefetches (h-independent) ----
        int           kn  = ctx[btn];
        unsigned char mnb = maskb[(size_t)btn << mshift];
        __half fr{}, fz{}, fn{};
        Q xnq[8];
        if constexpr (MODE == 0) {
            const int t2 = (t + 2 < T_) ? (t + 2) : (T_ - 1);
            const size_t o2 = (size_t)(bt0 + t2) * H_ + lane;
            fr = ipr[o2]; fz = ipz[o2]; fn = ipn[o2];
        } else {
            const float4* xr = (const float4*)(xf + (size_t)btn * H_);
#pragma unroll
            for (int q = 0; q < 8; q++) {
                float4 a = xr[2 * q], c = xr[2 * q + 1];
                xnq[q].h[0] = pkh2(a.x, a.y); xnq[q].h[1] = pkh2(a.z, a.w);
                xnq[q].h[2] = pkh2(c.x, c.y); xnq[q].h[3] = pkh2(c.z, c.w);
            }
        }

        // ---- input projection values ----
        float fir, fiz, fin;
        if constexpr (MODE == 0) {
            fir = __half2float(cr); fiz = __half2float(cz); fin = __half2float(cn);
        } else {
            float sr = bir, sz = biz, sn2 = bin;
#pragma unroll
            for (int q = 0; q < 8; q++) {
                Q wr, wz, wn;
                wr.u = swi[(0 * 8 + q) * 64 + lane];
                wz.u = swi[(1 * 8 + q) * 64 + lane];
                wn.u = swi[(2 * 8 + q) * 64 + lane];
#pragma unroll
                for (int p = 0; p < 4; p++) {
                    sr  = fdot2f(wr.h[p], xq[q].h[p], sr);
                    sz  = fdot2f(wz.h[p], xq[q].h[p], sz);
                    sn2 = fdot2f(wn.h[p], xq[q].h[p], sn2);
                }
            }
            fir = sr; fiz = sz; fin = sn2;
        }

        // ---- hidden matvec from registers, wave-uniform switch on expert ----
        float shr = 0.f, shz = 0.f, shn = 0.f;
        float bhrs, bhzs, bhns;
        switch (kc) {
        case 0:  MATVEC(w0); bhrs = bhr0; bhzs = bhz0; bhns = bhn0; break;
        case 1:  MATVEC(w1); bhrs = bhr1; bhzs = bhz1; bhns = bhn1; break;
        case 2:  MATVEC(w2); bhrs = bhr2; bhzs = bhz2; bhns = bhn2; break;
        default: MATVEC(w3); bhrs = bhr3; bhzs = bhz3; bhns = bhn3; break;
        }

        // ---- epilogue (in-lane) ----
        const float ar = shr + fir + bhrs;
        const float az = shz + fiz + bhzs;
        const float r  = 1.0f / (1.0f + __expf(-ar));
        const float z  = 1.0f / (1.0f + __expf(-az));
        const float a  = fin + r * (shn + bhns);
        const float n  = 2.0f / (1.0f + __expf(-2.0f * a)) - 1.0f;  // tanh, inf-safe
        float hnew = n + z * (hreg - n);
        hnew = (mc > 0.5f) ? hnew : hreg;
        hreg = hnew;

        // ---- same-wave h broadcast (double-buffered) ----
        hsc[t & 1][lane] = __float2half(hnew);
        __builtin_amdgcn_wave_barrier();
        {
            const uint4* hp = (const uint4*)hsc[t & 1];
#pragma unroll
            for (int q = 0; q < 8; q++) hq[q].u = hp[q];
        }
        __builtin_amdgcn_wave_barrier();

        // ---- logits (issued in the round-trip shadow) ----
        {
            float l0 = hnew * wo0, l1 = hnew * wo1;
#pragma unroll
            for (int m = 32; m >= 1; m >>= 1) {
                l0 += __shfl_xor(l0, m, 64);
                l1 += __shfl_xor(l1, m, 64);
            }
            if (lane == 0) *(float2*)(outp + t * 2) = make_float2(l0 + wob0, l1 + wob1);
        }

        // ---- rotate prefetched state ----
        if constexpr (MODE == 0) {
            cr = nr; cz = nz; cn = nn;
            nr = fr; nz = fz; nn = fn;
        } else {
#pragma unroll
            for (int q = 0; q < 8; q++) xq[q].u = xnq[q].u;
        }
        kc = __builtin_amdgcn_readfirstlane(kn);
        mc = mnb ? 1.0f : 0.0f;
    }
}

extern "C" void kernel_launch(void* const* d_in, const int* in_sizes, int n_in,
                              void* d_out, int out_size, void* d_ws, size_t ws_size,
                              hipStream_t stream) {
    const float* x    = (const float*)d_in[0];
    const int*   ctx  = (const int*)d_in[1];
    const void*  mask = d_in[2];
    const float* W_ir = (const float*)d_in[3];
    const float* W_iz = (const float*)d_in[4];
    const float* W_in = (const float*)d_in[5];
    const float* bir  = (const float*)d_in[6];
    const float* biz  = (const float*)d_in[7];
    const float* bin  = (const float*)d_in[8];
    const float* W_hr = (const float*)d_in[9];
    const float* W_hz = (const float*)d_in[10];
    const float* W_hn = (const float*)d_in[11];
    const float* bhr  = (const float*)d_in[12];
    const float* bhz  = (const float*)d_in[13];
    const float* bhn  = (const float*)d_in[14];
    const float* Wo_w = (const float*)d_in[15];
    const float* Wo_b = (const float*)d_in[16];

    char* ws = (char*)d_ws;
    __half* wht  = (__half*)ws;
    __half* wit  = (__half*)(ws + WS_WIT_OFF);
    int*    flag = (int*)(ws + WS_FLAG_OFF);
    __half* ipr  = (__half*)(ws + WS_IP_OFF);
    __half* ipz  = (__half*)(ws + WS_IP_OFF + IP_PLANE);
    __half* ipn  = (__half*)(ws + WS_IP_OFF + 2 * IP_PLANE);

    detect_mask_kernel<<<1, 256, 0, stream>>>((const unsigned char*)mask, flag);
    convert_weights_kernel<<<192, 256, 0, stream>>>(W_hr, W_hz, W_hn, W_ir, W_iz, W_in,
                                                    wht, wit);
    if (ws_size >= WS_A_NEED) {
        ip_prepass<<<512, 256, 0, stream>>>(x, wit, bir, biz, bin, ipr, ipz, ipn);
        gru_seq3<0><<<B_, 64, 0, stream>>>(x, ctx, (const unsigned char*)mask, flag,
                                           wht, wit, ipr, ipz, ipn,
                                           bir, biz, bin, bhr, bhz, bhn,
                                           Wo_w, Wo_b, (float*)d_out);
    } else {
        gru_seq3<1><<<B_, 64, 0, stream>>>(x, ctx, (const unsigned char*)mask, flag,
                                           wht, wit, ipr, ipz, ipn,
                                           bir, biz, bin, bhr, bhz, bhn,
                                           Wo_w, Wo_b, (float*)d_out);
    }
}

// Round 9
// 710.473 us; speedup vs baseline: 1.2059x; 1.2059x over previous
//
#include <hip/hip_runtime.h>
#include <hip/hip_fp16.h>

#define B_ 512
#define T_ 512
#define H_ 64
#define K_ 4

// ws layout:
//   wht  f16 [K*3][8][64][8]  @ 0        (98304 B)  chunk-transposed W_h
//   wit  f16 [3][8][64][8]    @ 98304    (24576 B)  chunk-transposed W_i
//   flag int                  @ 123136
//   xh16 f16 [B*T*H]          @ 131072   (33554432 B)
#define WS_WIT_OFF   98304
#define WS_FLAG_OFF  123136
#define WS_XH_OFF    131072

// dynamic LDS: W_h image [0, 98304) ; h scratch @98304 (2 waves x 2 bufs x 128 B)
#define LDS_H_OFF    98304
#define LDS_TOTAL    98816
#define STAGE_U4     6144      // 98304 / 16

typedef _Float16 half2_t __attribute__((ext_vector_type(2)));

union Q { uint4 u; half2_t h[4]; };  // 16 B = 4 packed half2

__device__ __forceinline__ float fdot2f(half2_t a, half2_t b, float c) {
#if __has_builtin(__builtin_amdgcn_fdot2)
    return __builtin_amdgcn_fdot2(a, b, c, false);
#else
    return fmaf((float)a[0], (float)b[0], fmaf((float)a[1], (float)b[1], c));
#endif
}

__device__ __forceinline__ half2_t pkh2(float a, float b) {
    return __builtin_bit_cast(half2_t, __builtin_amdgcn_cvt_pkrtz(a, b));
}

// Detect whether mask buffer is 1-byte bools or int32 0/1 (little-endian).
__global__ void detect_mask_kernel(const unsigned char* __restrict__ mb, int* __restrict__ flag) {
    __shared__ int cnt;
    if (threadIdx.x == 0) cnt = 0;
    __syncthreads();
    int c = 0;
    for (int i = threadIdx.x; i < 4096; i += blockDim.x)
        if ((i & 3) != 0 && mb[i] != 0) c++;
    atomicAdd(&cnt, c);
    __syncthreads();
    if (threadIdx.x == 0) *flag = (cnt > 0) ? 1 : 0;  // 1 => uint8 bools, 0 => int32
}

// Weights -> f16 chunk-transposed: dst u4 index (mat*8 + j/8)*64 + i
__global__ void convert_weights_kernel(const float* __restrict__ Whr, const float* __restrict__ Whz,
                                       const float* __restrict__ Whn, const float* __restrict__ Wir,
                                       const float* __restrict__ Wiz, const float* __restrict__ Win,
                                       __half* __restrict__ wht, __half* __restrict__ wit) {
    int idx = blockIdx.x * 256 + threadIdx.x;
    if (idx < K_ * 3 * H_ * H_) {
        int mat = idx >> 12;            // k*3+g
        int i   = (idx >> 6) & 63;
        int j   = idx & 63;
        int k   = mat / 3, g = mat - 3 * k;
        const float* src = (g == 0) ? Whr : (g == 1) ? Whz : Whn;
        wht[((mat * 8 + (j >> 3)) * 64 + i) * 8 + (j & 7)] = __float2half(src[(k * H_ + i) * H_ + j]);
    }
    if (idx < 3 * H_ * H_) {
        int g = idx >> 12;
        int i = (idx >> 6) & 63;
        int j = idx & 63;
        const float* src = (g == 0) ? Wir : (g == 1) ? Wiz : Win;
        wit[((g * 8 + (j >> 3)) * 64 + i) * 8 + (j & 7)] = __float2half(src[i * H_ + j]);
    }
}

// x f32 -> packed f16
__global__ void convert_x_kernel(const float* __restrict__ xf, __half* __restrict__ xh) {
    size_t i = (size_t)blockIdx.x * 256 + threadIdx.x;
    if (i >= (size_t)B_ * T_ * H_ / 8) return;
    const float4* p = (const float4*)xf + 2 * i;
    float4 a = p[0], b = p[1];
    Q o;
    o.h[0] = pkh2(a.x, a.y);
    o.h[1] = pkh2(a.z, a.w);
    o.h[2] = pkh2(b.x, b.y);
    o.h[3] = pkh2(b.z, b.w);
    ((uint4*)xh)[i] = o.u;
}

// Sequential GRU. 256 blocks x 128 threads = 2 independent waves (2 chains)
// sharing one 96 KB LDS image of all 4 experts' W_h. No barriers in the loop.
// W_i (3x64x64 f16) lives in 96 VGPRs per wave -> ip costs zero memory ops.
// Per-step LDS: 24 W_h ds_read_b128 + 9 h round-trip ops (was 57 in R6).
// lane = output row i; in-loop logits; h broadcast via per-wave LDS scratch
// (double-buffered + wave_barrier; same-wave DS pipe is in-order).
__global__ __launch_bounds__(128, 1)
void gru_seq4(const __half* __restrict__ xh16, const int* __restrict__ ctx,
              const unsigned char* __restrict__ maskb, const int* __restrict__ flagp,
              const __half* __restrict__ wht, const __half* __restrict__ wit,
              const float* __restrict__ b_ir, const float* __restrict__ b_iz,
              const float* __restrict__ b_in, const float* __restrict__ b_hr,
              const float* __restrict__ b_hz, const float* __restrict__ b_hn,
              const float* __restrict__ Wo_w, const float* __restrict__ Wo_b,
              float* __restrict__ out) {
    extern __shared__ __align__(16) char smem[];
    uint4* sw = (uint4*)smem;

    const int tid  = threadIdx.x;
    const int lane = tid & 63;
    const int wv   = tid >> 6;            // 0,1
    const int b    = blockIdx.x * 2 + wv;

    // ---- cooperative W_h staging (global -> LDS), once ----
    {
        const uint4* gsrc = (const uint4*)wht;
#pragma unroll 1
        for (int i = tid; i < STAGE_U4; i += 128) sw[i] = gsrc[i];
    }
    __syncthreads();

    const int flag   = *flagp;
    const int mshift = flag ? 0 : 2;
    const int bt0    = b * T_;

    // ---- W_i into 96 VGPRs ----
    Q wir[8], wiz[8], win[8];
    {
        const uint4* wu = (const uint4*)wit;
#pragma unroll
        for (int q = 0; q < 8; q++) {
            wir[q].u = wu[(0 * 8 + q) * 64 + lane];
            wiz[q].u = wu[(1 * 8 + q) * 64 + lane];
            win[q].u = wu[(2 * 8 + q) * 64 + lane];
        }
    }

    // biases: input (3) + all 4 experts' hidden (12)
    const float bir = b_ir[lane], biz = b_iz[lane], bin = b_in[lane];
    const float bhr0 = b_hr[lane],       bhz0 = b_hz[lane],       bhn0 = b_hn[lane];
    const float bhr1 = b_hr[64 + lane],  bhz1 = b_hz[64 + lane],  bhn1 = b_hn[64 + lane];
    const float bhr2 = b_hr[128 + lane], bhz2 = b_hz[128 + lane], bhn2 = b_hn[128 + lane];
    const float bhr3 = b_hr[192 + lane], bhz3 = b_hz[192 + lane], bhn3 = b_hn[192 + lane];

    const float wo0 = Wo_w[lane], wo1 = Wo_w[64 + lane];
    const float wob0 = Wo_b[0], wob1 = Wo_b[1];

    float hreg = 0.0f;
    Q hq[8];
#pragma unroll
    for (int q = 0; q < 8; q++) hq[q].u = make_uint4(0u, 0u, 0u, 0u);

    // per-wave h scratch (double-buffered)
    __half* hsc = (__half*)(smem + LDS_H_OFF + (wv << 8));

    // ---- prologue: x(0), ctx(0), mask(0) ----
    Q xpk[8];
    {
        const uint4* xp = (const uint4*)(xh16 + (size_t)bt0 * H_);
#pragma unroll
        for (int q = 0; q < 8; q++) xpk[q].u = xp[q];
    }
    int   kc = __builtin_amdgcn_readfirstlane(ctx[bt0]);
    float mc = maskb[(size_t)bt0 << mshift] ? 1.0f : 0.0f;

    float* outp = out + (size_t)b * T_ * 2;

#pragma unroll 1
    for (int t = 0; t < T_; t++) {
        const int tn  = (t + 1 < T_) ? (t + 1) : t;
        const int btn = bt0 + tn;

        // ---- W_h[kc] from LDS (24 conflict-free ds_read_b128) ----
        const uint4* whp = sw + kc * 1536 + lane;
        Q whrq[8], whzq[8], whnq[8];
#pragma unroll
        for (int q = 0; q < 8; q++) {
            whrq[q].u = whp[q * 64];
            whzq[q].u = whp[512 + q * 64];
            whnq[q].u = whp[1024 + q * 64];
        }

        // ---- prefetch t+1 inputs (h-independent) ----
        Q xnp[8];
        {
            const uint4* xp = (const uint4*)(xh16 + (size_t)btn * H_);
#pragma unroll
            for (int q = 0; q < 8; q++) xnp[q].u = xp[q];
        }
        int           kn  = ctx[btn];
        unsigned char mnb = maskb[(size_t)btn << mshift];

        // ---- input projection from register W_i (96 fdot2, zero mem ops) ----
        float sir = bir, siz = biz, sin_ = bin;
#pragma unroll
        for (int q = 0; q < 8; q++)
#pragma unroll
            for (int p = 0; p < 4; p++) {
                sir  = fdot2f(wir[q].h[p], xpk[q].h[p], sir);
                siz  = fdot2f(wiz[q].h[p], xpk[q].h[p], siz);
                sin_ = fdot2f(win[q].h[p], xpk[q].h[p], sin_);
            }

        // ---- hidden matvec (96 fdot2) ----
        float shr = 0.f, shz = 0.f, shn = 0.f;
#pragma unroll
        for (int q = 0; q < 8; q++)
#pragma unroll
            for (int p = 0; p < 4; p++) {
                shr = fdot2f(whrq[q].h[p], hq[q].h[p], shr);
                shz = fdot2f(whzq[q].h[p], hq[q].h[p], shz);
                shn = fdot2f(whnq[q].h[p], hq[q].h[p], shn);
            }

        // expert biases (wave-uniform select, no loads)
        const float bhrs = (kc == 0) ? bhr0 : (kc == 1) ? bhr1 : (kc == 2) ? bhr2 : bhr3;
        const float bhzs = (kc == 0) ? bhz0 : (kc == 1) ? bhz1 : (kc == 2) ? bhz2 : bhz3;
        const float bhns = (kc == 0) ? bhn0 : (kc == 1) ? bhn1 : (kc == 2) ? bhn2 : bhn3;

        // ---- epilogue (in-lane) ----
        const float ar = sir + shr + bhrs;
        const float az = siz + shz + bhzs;
        const float r  = 1.0f / (1.0f + __expf(-ar));
        const float z  = 1.0f / (1.0f + __expf(-az));
        const float a  = sin_ + r * (shn + bhns);
        const float n  = 2.0f / (1.0f + __expf(-2.0f * a)) - 1.0f;  // tanh, inf-safe
        float hnew = n + z * (hreg - n);
        hnew = (mc > 0.5f) ? hnew : hreg;
        hreg = hnew;

        // ---- same-wave h broadcast (double-buffered, order pinned) ----
        __half* hb = hsc + ((t & 1) << 6);
        hb[lane] = __float2half(hnew);
        __builtin_amdgcn_wave_barrier();
        {
            const uint4* hp = (const uint4*)hb;
#pragma unroll
            for (int q = 0; q < 8; q++) hq[q].u = hp[q];
        }
        __builtin_amdgcn_wave_barrier();

        // ---- logits (issued in the round-trip shadow) ----
        {
            float l0 = hnew * wo0, l1 = hnew * wo1;
#pragma unroll
            for (int m = 32; m >= 1; m >>= 1) {
                l0 += __shfl_xor(l0, m, 64);
                l1 += __shfl_xor(l1, m, 64);
            }
            if (lane == 0) *(float2*)(outp + t * 2) = make_float2(l0 + wob0, l1 + wob1);
        }

        // ---- rotate prefetched state ----
#pragma unroll
        for (int q = 0; q < 8; q++) xpk[q].u = xnp[q].u;
        kc = __builtin_amdgcn_readfirstlane(kn);
        mc = mnb ? 1.0f : 0.0f;
    }
}

extern "C" void kernel_launch(void* const* d_in, const int* in_sizes, int n_in,
                              void* d_out, int out_size, void* d_ws, size_t ws_size,
                              hipStream_t stream) {
    const float* x    = (const float*)d_in[0];
    const int*   ctx  = (const int*)d_in[1];
    const void*  mask = d_in[2];
    const float* W_ir = (const float*)d_in[3];
    const float* W_iz = (const float*)d_in[4];
    const float* W_in = (const float*)d_in[5];
    const float* bir  = (const float*)d_in[6];
    const float* biz  = (const float*)d_in[7];
    const float* bin  = (const float*)d_in[8];
    const float* W_hr = (const float*)d_in[9];
    const float* W_hz = (const float*)d_in[10];
    const float* W_hn = (const float*)d_in[11];
    const float* bhr  = (const float*)d_in[12];
    const float* bhz  = (const float*)d_in[13];
    const float* bhn  = (const float*)d_in[14];
    const float* Wo_w = (const float*)d_in[15];
    const float* Wo_b = (const float*)d_in[16];

    char* ws = (char*)d_ws;
    __half* wht  = (__half*)ws;
    __half* wit  = (__half*)(ws + WS_WIT_OFF);
    int*    flag = (int*)(ws + WS_FLAG_OFF);
    __half* xh16 = (__half*)(ws + WS_XH_OFF);

    detect_mask_kernel<<<1, 256, 0, stream>>>((const unsigned char*)mask, flag);
    convert_weights_kernel<<<192, 256, 0, stream>>>(W_hr, W_hz, W_hn, W_ir, W_iz, W_in,
                                                    wht, wit);
    convert_x_kernel<<<8192, 256, 0, stream>>>(x, xh16);

    (void)hipFuncSetAttribute((const void*)gru_seq4,
                              hipFuncAttributeMaxDynamicSharedMemorySize, LDS_TOTAL);
    gru_seq4<<<B_ / 2, 128, LDS_TOTAL, stream>>>(
        xh16, ctx, (const unsigned char*)mask, flag, wht, wit,
        bir, biz, bin, bhr, bhz, bhn, Wo_w, Wo_b, (float*)d_out);
}